// Round 5
// baseline (515.283 us; speedup 1.0000x reference)
//
#include <hip/hip_runtime.h>
#include <math.h>

#define L_SEQ 8192
#define NFFT  16384     // conv length
#define N2    8192      // packed complex FFT length
#define N4    4096      // half (radix-2 block) length
#define CCH   768
#define BB    4
#define EDIM  33
#define ODIM  64
#define BLK   512

#define C_PI8 0.9238795325112867f
#define S_PI8 0.3826834323650898f
#define C_PI4 0.7071067811865476f

// ---------- complex helpers ----------
__device__ __forceinline__ float2 cadd(float2 a, float2 b) { return make_float2(a.x + b.x, a.y + b.y); }
__device__ __forceinline__ float2 csub(float2 a, float2 b) { return make_float2(a.x - b.x, a.y - b.y); }
__device__ __forceinline__ float2 cmul(float2 a, float2 b) {
  return make_float2(fmaf(a.x, b.x, -a.y * b.y), fmaf(a.x, b.y, a.y * b.x));
}
// a * conj(w)
__device__ __forceinline__ float2 cmulc(float2 a, float2 w) {
  return make_float2(fmaf(a.x, w.x, a.y * w.y), fmaf(a.y, w.x, -a.x * w.y));
}
__device__ __forceinline__ float2 cconj(float2 a) { return make_float2(a.x, -a.y); }

// LDS swizzle: fold bits 4-11 into the bank nibble (bijective; bits>=4 unchanged).
__device__ __forceinline__ int swz(int i) { return i ^ ((i >> 4) & 15) ^ ((i >> 8) & 15); }

// reverse 6 base-4 digits of a 12-bit index
__device__ __forceinline__ int rev4_12(int v) {
  int r = 0;
#pragma unroll
  for (int i = 0; i < 6; ++i) { r = (r << 2) | (v & 3); v >>= 2; }
  return r;
}
// bin f (0..8191) of packed FFT -> LDS position after DIF (r2 first, then 3 fused r16)
__device__ __forceinline__ int pos8(int f) { return ((f & 1) << 12) | rev4_12(f >> 1); }

// ---------- radix-4 butterflies ----------
__device__ __forceinline__ void dif4(float2& x0, float2& x1, float2& x2, float2& x3,
                                     float2 w1, float2 w2, float2 w3) {
  float2 a = cadd(x0, x2), b = csub(x0, x2);
  float2 c = cadd(x1, x3), d = csub(x1, x3);
  x0 = cadd(a, c);
  x1 = cmul(make_float2(b.x + d.y, b.y - d.x), w1);
  x2 = cmul(csub(a, c), w2);
  x3 = cmul(make_float2(b.x - d.y, b.y + d.x), w3);
}
__device__ __forceinline__ void dif4_nw(float2& x0, float2& x1, float2& x2, float2& x3) {
  float2 a = cadd(x0, x2), b = csub(x0, x2);
  float2 c = cadd(x1, x3), d = csub(x1, x3);
  x0 = cadd(a, c);
  x1 = make_float2(b.x + d.y, b.y - d.x);
  x2 = csub(a, c);
  x3 = make_float2(b.x - d.y, b.y + d.x);
}
// DIT: inputs 1..3 pre-multiplied by conj(w)
__device__ __forceinline__ void dit4(float2& x0, float2& x1, float2& x2, float2& x3,
                                     float2 w1, float2 w2, float2 w3) {
  float2 t0 = x0, t1 = cmulc(x1, w1), t2 = cmulc(x2, w2), t3 = cmulc(x3, w3);
  float2 a = cadd(t0, t2), b = csub(t0, t2);
  float2 c = cadd(t1, t3), d = csub(t1, t3);
  x0 = cadd(a, c);
  x1 = make_float2(b.x - d.y, b.y + d.x);
  x2 = csub(a, c);
  x3 = make_float2(b.x + d.y, b.y - d.x);
}
__device__ __forceinline__ void dit4_nw(float2& x0, float2& x1, float2& x2, float2& x3) {
  float2 a = cadd(x0, x2), b = csub(x0, x2);
  float2 c = cadd(x1, x3), d = csub(x1, x3);
  x0 = cadd(a, c);
  x1 = make_float2(b.x - d.y, b.y + d.x);
  x2 = csub(a, c);
  x3 = make_float2(b.x + d.y, b.y - d.x);
}

// triple-table read: entry = {w1, w2, w3, pad} as 2x float4
__device__ __forceinline__ void ld3(const float4* __restrict__ tab, int idx,
                                    float2& w1, float2& w2, float2& w3) {
  float4 a = tab[2 * idx];
  float4 b = tab[2 * idx + 1];
  w1 = make_float2(a.x, a.y);
  w2 = make_float2(a.z, a.w);
  w3 = make_float2(b.x, b.y);
}

// ---------- twiddle + triple tables ----------
// tw[r] = W^r = exp(-2pi i r/16384)
// T4 [t*256+u] = triples of e = 4u  + 1024t   (fwd A stageA, inv C stageB)
// T16[u]       = triples of e = 16u           (fwd A stageB, inv C stageA)
// T64[t*16+u]  = triples of e = 64u + 1024t   (fwd B stageA, inv B stageB)
// T256[u]      = triples of e = 256u          (fwd B stageB, inv B stageA)
__global__ void twiddle_kernel(float2* __restrict__ tw, float4* __restrict__ T4,
                               float4* __restrict__ T16, float4* __restrict__ T64,
                               float4* __restrict__ T256) {
  const int r = blockIdx.x * blockDim.x + threadIdx.x;
  const float C = (float)(6.283185307179586476925286766559 / 16384.0);
  if (r < NFFT) {
    float s, c;
    sincosf(C * (float)r, &s, &c);
    tw[r] = make_float2(c, -s);
  }
  const int j = r - NFFT;
  float4* tab = nullptr;
  int idx = 0, e = 0;
  if (j >= 0 && j < 1024)      { tab = T4;   idx = j;        e = 4 * (j & 255) + 1024 * (j >> 8); }
  else if (j >= 1024 && j < 1280) { tab = T16;  idx = j - 1024; e = 16 * idx; }
  else if (j >= 1280 && j < 1344) { tab = T64;  idx = j - 1280; e = 64 * (idx & 15) + 1024 * (idx >> 4); }
  else if (j >= 1344 && j < 1360) { tab = T256; idx = j - 1344; e = 256 * idx; }
  if (tab) {
    float s1, c1, s2, c2, s3, c3;
    sincosf(C * (float)e, &s1, &c1);
    sincosf(C * (float)(2 * e), &s2, &c2);
    sincosf(C * (float)(3 * e), &s3, &c3);
    tab[2 * idx]     = make_float4(c1, -s1, c2, -s2);
    tab[2 * idx + 1] = make_float4(c3, -s3, 0.f, 0.f);
  }
}

// ---------- MLP: h[o][l], 16-way o-split, 1024 threads / 64 l per block ----------
__global__ __launch_bounds__(1024) void mlp_kernel(
    const float* __restrict__ z, const float* __restrict__ freq,
    const float* __restrict__ w0, const float* __restrict__ b0,
    const float* __restrict__ w1, const float* __restrict__ b1,
    const float* __restrict__ w2, const float* __restrict__ b2,
    float* __restrict__ h)            // [64][L]
{
  __shared__ float zs[64][EDIM];      // stride 33: conflict-free
  __shared__ float hs[2][64][ODIM + 1];
  const int tid = threadIdx.x;
  const int l0 = blockIdx.x * 64;
  for (int i = tid; i < 64 * EDIM; i += 1024) {
    int ll = i / EDIM, e = i % EDIM;
    zs[ll][e] = z[(l0 + ll) * EDIM + e];
  }
  __syncthreads();
  const int li = tid & 63;
  const int o0 = (tid >> 6) * 4;       // wave-uniform
  float fr[4], acc[4];
#pragma unroll
  for (int k = 0; k < 4; ++k) { fr[k] = freq[o0 + k]; acc[k] = b0[o0 + k]; }
#pragma unroll
  for (int e = 0; e < EDIM; ++e) {
    float zv = zs[li][e];
#pragma unroll
    for (int k = 0; k < 4; ++k) acc[k] = fmaf(zv, w0[e * ODIM + o0 + k], acc[k]);
  }
#pragma unroll
  for (int k = 0; k < 4; ++k) hs[0][li][o0 + k] = sinf(fr[k] * acc[k]);
  __syncthreads();
#pragma unroll
  for (int k = 0; k < 4; ++k) acc[k] = b1[o0 + k];
#pragma unroll
  for (int i = 0; i < ODIM; ++i) {
    float hv = hs[0][li][i];
#pragma unroll
    for (int k = 0; k < 4; ++k) acc[k] = fmaf(hv, w1[i * ODIM + o0 + k], acc[k]);
  }
#pragma unroll
  for (int k = 0; k < 4; ++k) hs[1][li][o0 + k] = sinf(fr[k] * acc[k]);
  __syncthreads();
#pragma unroll
  for (int k = 0; k < 4; ++k) acc[k] = b2[o0 + k];
#pragma unroll
  for (int i = 0; i < ODIM; ++i) {
    float hv = hs[1][li][i];
#pragma unroll
    for (int k = 0; k < 4; ++k) acc[k] = fmaf(hv, w2[i * ODIM + o0 + k], acc[k]);
  }
#pragma unroll
  for (int k = 0; k < 4; ++k) h[(size_t)(o0 + k) * L_SEQ + l0 + li] = sinf(fr[k] * acc[k]);
}

// ---------- kout: 64x64 tile, 4x4 register micro-tile GEMM + modulation ----------
__global__ __launch_bounds__(256) void kout_kernel(
    const float* __restrict__ h, const float* __restrict__ wout,
    const float* __restrict__ t, const float* __restrict__ deltas,
    float* __restrict__ k)            // [768][L]
{
  __shared__ float hT[ODIM][64];
  __shared__ float wT[ODIM][64];
  const int lb = blockIdx.x % (L_SEQ / 64);
  const int cb = blockIdx.x / (L_SEQ / 64);
  const int l0 = lb * 64, c0 = cb * 64;
  const int tid = threadIdx.x;
  for (int i = tid; i < ODIM * 16; i += 256) {
    int o = i >> 4, lq = (i & 15) * 4;
    *(float4*)&hT[o][lq] = *(const float4*)&h[(size_t)o * L_SEQ + l0 + lq];
  }
  for (int i = tid; i < ODIM * 16; i += 256) {
    int o = i >> 4, cq = (i & 15) * 4;
    *(float4*)&wT[o][cq] = *(const float4*)&wout[(size_t)o * CCH + c0 + cq];
  }
  __syncthreads();
  const int li = tid & 15, ci = tid >> 4;
  float acc[4][4];
#pragma unroll
  for (int a = 0; a < 4; ++a)
#pragma unroll
    for (int b = 0; b < 4; ++b) acc[a][b] = 0.f;
#pragma unroll 8
  for (int o = 0; o < ODIM; ++o) {
    float4 h4 = *(const float4*)&hT[o][li * 4];
    float4 w4 = *(const float4*)&wT[o][ci * 4];
    const float ha[4] = {h4.x, h4.y, h4.z, h4.w};
    const float wa[4] = {w4.x, w4.y, w4.z, w4.w};
#pragma unroll
    for (int a = 0; a < 4; ++a)
#pragma unroll
      for (int b = 0; b < 4; ++b) acc[a][b] = fmaf(ha[a], wa[b], acc[a][b]);
  }
  float4 t4 = *(const float4*)&t[l0 + li * 4];
  const float ta[4] = {t4.x, t4.y, t4.z, t4.w};
#pragma unroll
  for (int b = 0; b < 4; ++b) {
    const int c = c0 + ci * 4 + b;
    const float dl = fabsf(deltas[c]);
    float4 r;
    r.x = acc[0][b] * expf(-ta[0] * dl);
    r.y = acc[1][b] * expf(-ta[1] * dl);
    r.z = acc[2][b] * expf(-ta[2] * dl);
    r.w = acc[3][b] * expf(-ta[3] * dl);
    *(float4*)&k[(size_t)c * L_SEQ + l0 + li * 4] = r;
  }
}

// ---------- FFT rounds (8192 = r2 x 4096, two halves; 3 fused radix-16 rounds) ----------

// fwd round A fused with global load + radix-2 zero-pad twiddle (upper half)
__device__ __forceinline__ void fwd_roundA(float2* Z, const float2* __restrict__ src,
                                           const float2* __restrict__ tw,
                                           const float4* __restrict__ T4,
                                           const float4* __restrict__ T16, int tid) {
  const int h = tid >> 8, u = tid & 255;
  float2 e[4][4];
#pragma unroll
  for (int s = 0; s < 4; ++s)
#pragma unroll
    for (int t = 0; t < 4; ++t) {
      const int gi = u + s * 1024 + t * 256;
      float2 v = src[gi];
      if (h) v = cmul(v, tw[2 * gi]);
      e[s][t] = v;
    }
#pragma unroll
  for (int t = 0; t < 4; ++t) {            // stage A: span 1024, e = 4u + 1024t
    float2 w1, w2, w3;
    ld3(T4, t * 256 + u, w1, w2, w3);
    dif4(e[0][t], e[1][t], e[2][t], e[3][t], w1, w2, w3);
  }
  {                                         // stage B: span 256, e = 16u
    float2 w1, w2, w3;
    ld3(T16, u, w1, w2, w3);
#pragma unroll
    for (int s = 0; s < 4; ++s) dif4(e[s][0], e[s][1], e[s][2], e[s][3], w1, w2, w3);
  }
  const int base = (h << 12) + u;
#pragma unroll
  for (int s = 0; s < 4; ++s)
#pragma unroll
    for (int t = 0; t < 4; ++t) Z[swz(base + s * 1024 + t * 256)] = e[s][t];
}

__device__ __forceinline__ void fwd_roundB(float2* Z, const float4* __restrict__ T64,
                                           const float4* __restrict__ T256, int tid) {
  const int u = tid & 15, g = (tid >> 4) & 15, h = tid >> 8;
  const int base = (h << 12) + (g << 8) + u;
  int adr[4][4];
#pragma unroll
  for (int s = 0; s < 4; ++s)
#pragma unroll
    for (int t = 0; t < 4; ++t) adr[s][t] = swz(base + s * 64 + t * 16);
  float2 e[4][4];
#pragma unroll
  for (int s = 0; s < 4; ++s)
#pragma unroll
    for (int t = 0; t < 4; ++t) e[s][t] = Z[adr[s][t]];
#pragma unroll
  for (int t = 0; t < 4; ++t) {            // stage A: span 64, e = 64u + 1024t
    float2 w1, w2, w3;
    ld3(T64, t * 16 + u, w1, w2, w3);
    dif4(e[0][t], e[1][t], e[2][t], e[3][t], w1, w2, w3);
  }
  {                                         // stage B: span 16, e = 256u
    float2 w1, w2, w3;
    ld3(T256, u, w1, w2, w3);
#pragma unroll
    for (int s = 0; s < 4; ++s) dif4(e[s][0], e[s][1], e[s][2], e[s][3], w1, w2, w3);
  }
#pragma unroll
  for (int s = 0; s < 4; ++s)
#pragma unroll
    for (int t = 0; t < 4; ++t) Z[adr[s][t]] = e[s][t];
}

__device__ __forceinline__ void fwd_roundC(float2* Z, int tid) {
  const int h = tid >> 8, jp = tid & 255;
  const int base = (h << 12) + (jp << 4);
  int adr[4][4];
#pragma unroll
  for (int s = 0; s < 4; ++s)
#pragma unroll
    for (int t = 0; t < 4; ++t) adr[s][t] = swz(base + s * 4 + t);
  float2 e[4][4];
#pragma unroll
  for (int s = 0; s < 4; ++s)
#pragma unroll
    for (int t = 0; t < 4; ++t) e[s][t] = Z[adr[s][t]];
  // stage A: span 4, e = 1024t (constants; t=0 unit)
  dif4_nw(e[0][0], e[1][0], e[2][0], e[3][0]);
  dif4(e[0][1], e[1][1], e[2][1], e[3][1],
       make_float2(C_PI8, -S_PI8), make_float2(C_PI4, -C_PI4), make_float2(S_PI8, -C_PI8));
  dif4(e[0][2], e[1][2], e[2][2], e[3][2],
       make_float2(C_PI4, -C_PI4), make_float2(0.f, -1.f), make_float2(-C_PI4, -C_PI4));
  dif4(e[0][3], e[1][3], e[2][3], e[3][3],
       make_float2(S_PI8, -C_PI8), make_float2(-C_PI4, -C_PI4), make_float2(-C_PI8, S_PI8));
  // stage B: span 1, unit twiddles
#pragma unroll
  for (int s = 0; s < 4; ++s) dif4_nw(e[s][0], e[s][1], e[s][2], e[s][3]);
#pragma unroll
  for (int s = 0; s < 4; ++s)
#pragma unroll
    for (int t = 0; t < 4; ++t) Z[adr[s][t]] = e[s][t];
}

__device__ __forceinline__ void inv_roundA(float2* Z, int tid) {
  const int h = tid >> 8, jp = tid & 255;
  const int base = (h << 12) + (jp << 4);
  int adr[4][4];
#pragma unroll
  for (int s = 0; s < 4; ++s)
#pragma unroll
    for (int t = 0; t < 4; ++t) adr[s][t] = swz(base + s * 4 + t);
  float2 e[4][4];
#pragma unroll
  for (int s = 0; s < 4; ++s)
#pragma unroll
    for (int t = 0; t < 4; ++t) e[s][t] = Z[adr[s][t]];
  // stage A: span 1 over t, unit
#pragma unroll
  for (int s = 0; s < 4; ++s) dit4_nw(e[s][0], e[s][1], e[s][2], e[s][3]);
  // stage B: span 4 over s, e = 1024t (conj applied inside dit4)
  dit4_nw(e[0][0], e[1][0], e[2][0], e[3][0]);
  dit4(e[0][1], e[1][1], e[2][1], e[3][1],
       make_float2(C_PI8, -S_PI8), make_float2(C_PI4, -C_PI4), make_float2(S_PI8, -C_PI8));
  dit4(e[0][2], e[1][2], e[2][2], e[3][2],
       make_float2(C_PI4, -C_PI4), make_float2(0.f, -1.f), make_float2(-C_PI4, -C_PI4));
  dit4(e[0][3], e[1][3], e[2][3], e[3][3],
       make_float2(S_PI8, -C_PI8), make_float2(-C_PI4, -C_PI4), make_float2(-C_PI8, S_PI8));
#pragma unroll
  for (int s = 0; s < 4; ++s)
#pragma unroll
    for (int t = 0; t < 4; ++t) Z[adr[s][t]] = e[s][t];
}

__device__ __forceinline__ void inv_roundB(float2* Z, const float4* __restrict__ T64,
                                           const float4* __restrict__ T256, int tid) {
  const int u = tid & 15, g = (tid >> 4) & 15, h = tid >> 8;
  const int base = (h << 12) + (g << 8) + u;
  int adr[4][4];
#pragma unroll
  for (int s = 0; s < 4; ++s)
#pragma unroll
    for (int t = 0; t < 4; ++t) adr[s][t] = swz(base + s * 64 + t * 16);
  float2 e[4][4];
#pragma unroll
  for (int s = 0; s < 4; ++s)
#pragma unroll
    for (int t = 0; t < 4; ++t) e[s][t] = Z[adr[s][t]];
  {                                         // stage A: span 16 over t, e = 256u
    float2 w1, w2, w3;
    ld3(T256, u, w1, w2, w3);
#pragma unroll
    for (int s = 0; s < 4; ++s) dit4(e[s][0], e[s][1], e[s][2], e[s][3], w1, w2, w3);
  }
#pragma unroll
  for (int t = 0; t < 4; ++t) {            // stage B: span 64 over s, e = 64u + 1024t
    float2 w1, w2, w3;
    ld3(T64, t * 16 + u, w1, w2, w3);
    dit4(e[0][t], e[1][t], e[2][t], e[3][t], w1, w2, w3);
  }
#pragma unroll
  for (int s = 0; s < 4; ++s)
#pragma unroll
    for (int t = 0; t < 4; ++t) Z[adr[s][t]] = e[s][t];
}

__device__ __forceinline__ void inv_roundC(float2* Z, const float4* __restrict__ T4,
                                           const float4* __restrict__ T16, int tid) {
  const int h = tid >> 8, u = tid & 255;
  const int base = (h << 12) + u;
  int adr[4][4];
#pragma unroll
  for (int s = 0; s < 4; ++s)
#pragma unroll
    for (int t = 0; t < 4; ++t) adr[s][t] = swz(base + s * 1024 + t * 256);
  float2 e[4][4];
#pragma unroll
  for (int s = 0; s < 4; ++s)
#pragma unroll
    for (int t = 0; t < 4; ++t) e[s][t] = Z[adr[s][t]];
  {                                         // stage A: span 256 over t, e = 16u
    float2 w1, w2, w3;
    ld3(T16, u, w1, w2, w3);
#pragma unroll
    for (int s = 0; s < 4; ++s) dit4(e[s][0], e[s][1], e[s][2], e[s][3], w1, w2, w3);
  }
#pragma unroll
  for (int t = 0; t < 4; ++t) {            // stage B: span 1024 over s, e = 4u + 1024t
    float2 w1, w2, w3;
    ld3(T4, t * 256 + u, w1, w2, w3);
    dit4(e[0][t], e[1][t], e[2][t], e[3][t], w1, w2, w3);
  }
#pragma unroll
  for (int s = 0; s < 4; ++s)
#pragma unroll
    for (int t = 0; t < 4; ++t) Z[adr[s][t]] = e[s][t];
}

// ---------- kfft: one channel per WG; store K half-spectrum ----------
__global__ __launch_bounds__(BLK) void kfft_kernel(
    const float* __restrict__ kf, const float2* __restrict__ tw,
    const float4* __restrict__ T4, const float4* __restrict__ T16,
    const float4* __restrict__ T64, const float4* __restrict__ T256,
    float2* __restrict__ Kf)
{
  extern __shared__ float2 Z[];
  const int c = blockIdx.x, tid = threadIdx.x;
  const float2* k2 = (const float2*)(kf + (size_t)c * L_SEQ);
  fwd_roundA(Z, k2, tw, T4, T16, tid);
  __syncthreads();
  fwd_roundB(Z, T64, T256, tid);
  __syncthreads();
  fwd_roundC(Z, tid);
  __syncthreads();

  float2* Kc = Kf + (size_t)c * N2;
#pragma unroll
  for (int s2 = 0; s2 < 8; ++s2) {
    const int f = tid + s2 * BLK;
    if (f == 0) {
      float2 z0 = Z[swz(0)];
      Kc[0] = make_float2(z0.x + z0.y, z0.x - z0.y);   // (K[0], K[8192]) both real
      float2 z4 = Z[swz(2)];                            // pos8(4096)==2
      Kc[N4] = make_float2(z4.x, -z4.y);                // K[4096] = conj(Z[4096])
    } else {
      float2 zf = Z[swz(pos8(f))];
      float2 zg = Z[swz(pos8(N2 - f))];
      float2 E = make_float2(0.5f * (zf.x + zg.x), 0.5f * (zf.y - zg.y));
      float2 O = make_float2(0.5f * (zf.y + zg.y), -0.5f * (zf.x - zg.x));
      float2 wO = cmul(tw[f], O);
      Kc[f]      = cadd(E, wO);
      Kc[N2 - f] = cconj(csub(E, wO));
    }
  }
}

// ---------- conv: one (b,c) row per WG ----------
__global__ __launch_bounds__(BLK) void conv_kernel(
    const float* __restrict__ x, const float2* __restrict__ Kf,
    const float* __restrict__ bias, const float2* __restrict__ tw,
    const float4* __restrict__ T4, const float4* __restrict__ T16,
    const float4* __restrict__ T64, const float4* __restrict__ T256,
    float* __restrict__ out)
{
  extern __shared__ float2 Z[];
  const int tid = threadIdx.x;
  const int c = blockIdx.x % CCH;
  const int b = blockIdx.x / CCH;
  const float2* x2 = (const float2*)(x + (size_t)(b * CCH + c) * L_SEQ);

  fwd_roundA(Z, x2, tw, T4, T16, tid);
  __syncthreads();
  fwd_roundB(Z, T64, T256, tid);
  __syncthreads();
  fwd_roundC(Z, tid);
  __syncthreads();

  // unpack X, multiply by K, repack spectrum of w = y_even + i*y_odd
  const float2* Kc = Kf + (size_t)c * N2;
  const float scale = 1.0f / (float)NFFT;
#pragma unroll
  for (int s2 = 0; s2 < 8; ++s2) {
    const int f = tid + s2 * BLK;
    if (f == 0) {
      float2 z0 = Z[swz(0)];
      float2 k0 = Kc[0];
      float Y0 = (z0.x + z0.y) * k0.x * scale;
      float Y8 = (z0.x - z0.y) * k0.y * scale;
      Z[swz(0)] = make_float2(0.5f * (Y0 + Y8), 0.5f * (Y0 - Y8));
      float2 z4 = Z[swz(2)];
      float2 k4 = Kc[N4];
      float2 Y4 = cmul(make_float2(z4.x, -z4.y), k4);
      Y4.x *= scale; Y4.y *= scale;
      Z[swz(2)] = cconj(Y4);
    } else {
      const int p  = swz(pos8(f));
      const int pq = swz(pos8(N2 - f));
      float2 zf = Z[p], zg = Z[pq];
      float2 E = make_float2(0.5f * (zf.x + zg.x), 0.5f * (zf.y - zg.y));
      float2 O = make_float2(0.5f * (zf.y + zg.y), -0.5f * (zf.x - zg.x));
      float2 w = tw[f];
      float2 wO = cmul(w, O);
      float2 P = cadd(E, wO);                     // X[f]
      float2 M = csub(E, wO);                     // conj(X[8192-f])
      float2 Yf  = cmul(P, Kc[f]);
      float2 Ygc = cmul(M, cconj(Kc[N2 - f]));    // conj(Y[8192-f])
      Yf.x *= scale; Yf.y *= scale; Ygc.x *= scale; Ygc.y *= scale;
      float2 A  = make_float2(0.5f * (Yf.x + Ygc.x), 0.5f * (Yf.y + Ygc.y));
      float2 Bc = make_float2(0.5f * (Yf.x - Ygc.x), 0.5f * (Yf.y - Ygc.y));
      float2 cb  = cmul(cconj(w), Bc);
      Z[p]  = make_float2(A.x - cb.y, A.y + cb.x);
      float2 cb2 = cmul(w, cconj(Bc));
      Z[pq] = make_float2(A.x - cb2.y, -A.y + cb2.x);
    }
  }
  __syncthreads();
  inv_roundA(Z, tid);
  __syncthreads();
  inv_roundB(Z, T64, T256, tid);
  __syncthreads();
  inv_roundC(Z, T4, T16, tid);
  __syncthreads();

  // fused final radix-2 DIT (low half only) + epilogue, float2 stores
  const float bc = bias[c];
  float2* o2 = (float2*)(out + (size_t)(b * CCH + c) * L_SEQ);
#pragma unroll
  for (int i = tid; i < N4; i += BLK) {
    float2 a = Z[swz(i)];
    float2 bb = cmul(Z[swz(i + N4)], cconj(tw[2 * i]));
    float2 xv = x2[i];
    o2[i] = make_float2(a.x + bb.x + xv.x * bc, a.y + bb.y + xv.y * bc);
  }
}

extern "C" void kernel_launch(void* const* d_in, const int* in_sizes, int n_in,
                              void* d_out, int out_size, void* d_ws, size_t ws_size,
                              hipStream_t stream) {
  const float* x      = (const float*)d_in[0];
  const float* bias   = (const float*)d_in[1];
  const float* z      = (const float*)d_in[2];
  const float* t      = (const float*)d_in[3];
  const float* deltas = (const float*)d_in[4];
  const float* freq   = (const float*)d_in[5];
  const float* w0     = (const float*)d_in[6];
  const float* b0     = (const float*)d_in[7];
  const float* w1     = (const float*)d_in[8];
  const float* b1     = (const float*)d_in[9];
  const float* w2     = (const float*)d_in[10];
  const float* b2     = (const float*)d_in[11];
  const float* wout   = (const float*)d_in[12];
  float* out = (float*)d_out;

  // ws layout: [tw 128K][T4 32K][T16 8K][T64 2K][T256 .5K][h 2M][kfilt 24M][Kf 48M]
  char* p = (char*)d_ws;
  float2* tw   = (float2*)p;             p += (size_t)NFFT * sizeof(float2);
  float4* T4   = (float4*)p;             p += (size_t)1024 * 2 * sizeof(float4);
  float4* T16  = (float4*)p;             p += (size_t)256 * 2 * sizeof(float4);
  float4* T64  = (float4*)p;             p += (size_t)64 * 2 * sizeof(float4);
  float4* T256 = (float4*)p;             p += (size_t)16 * 2 * sizeof(float4);
  float*  h    = (float*)p;              p += (size_t)ODIM * L_SEQ * sizeof(float);
  float*  kfilt= (float*)p;              p += (size_t)CCH * L_SEQ * sizeof(float);
  float2* Kf   = (float2*)p;

  twiddle_kernel<<<70, 256, 0, stream>>>(tw, T4, T16, T64, T256);
  mlp_kernel<<<L_SEQ / 64, 1024, 0, stream>>>(z, freq, w0, b0, w1, b1, w2, b2, h);
  kout_kernel<<<(L_SEQ / 64) * (CCH / 64), 256, 0, stream>>>(h, wout, t, deltas, kfilt);

  const size_t lds = (size_t)N2 * sizeof(float2);   // 64 KB
  hipFuncSetAttribute(reinterpret_cast<const void*>(kfft_kernel),
                      hipFuncAttributeMaxDynamicSharedMemorySize, lds);
  hipFuncSetAttribute(reinterpret_cast<const void*>(conv_kernel),
                      hipFuncAttributeMaxDynamicSharedMemorySize, lds);
  kfft_kernel<<<CCH, BLK, lds, stream>>>(kfilt, tw, T4, T16, T64, T256, Kf);
  conv_kernel<<<BB * CCH, BLK, lds, stream>>>(x, Kf, bias, tw, T4, T16, T64, T256, out);
}

// Round 6
// 342.000 us; speedup vs baseline: 1.5067x; 1.5067x over previous
//
#include <hip/hip_runtime.h>
#include <math.h>

#define L_SEQ 8192
#define NFFT  16384     // conv length
#define N2    8192      // packed complex FFT length
#define N4    4096      // half (radix-2 block) length
#define CCH   768
#define BB    4
#define EDIM  33
#define ODIM  64
#define BLK   512

#define C_PI8 0.9238795325112867f
#define S_PI8 0.3826834323650898f
#define C_PI4 0.7071067811865476f

// ---------- complex helpers ----------
__device__ __forceinline__ float2 cadd(float2 a, float2 b) { return make_float2(a.x + b.x, a.y + b.y); }
__device__ __forceinline__ float2 csub(float2 a, float2 b) { return make_float2(a.x - b.x, a.y - b.y); }
__device__ __forceinline__ float2 cmul(float2 a, float2 b) {
  return make_float2(fmaf(a.x, b.x, -a.y * b.y), fmaf(a.x, b.y, a.y * b.x));
}
// a * conj(w)
__device__ __forceinline__ float2 cmulc(float2 a, float2 w) {
  return make_float2(fmaf(a.x, w.x, a.y * w.y), fmaf(a.y, w.x, -a.x * w.y));
}
__device__ __forceinline__ float2 cconj(float2 a) { return make_float2(a.x, -a.y); }

// LDS swizzle: fold bits 4-11 into the bank nibble (bijective; bits>=4 unchanged).
__device__ __forceinline__ int swz(int i) { return i ^ ((i >> 4) & 15) ^ ((i >> 8) & 15); }

// reverse 6 base-4 digits of a 12-bit index
__device__ __forceinline__ int rev4_12(int v) {
  int r = 0;
#pragma unroll
  for (int i = 0; i < 6; ++i) { r = (r << 2) | (v & 3); v >>= 2; }
  return r;
}
// bin f (0..8191) of packed FFT -> LDS position after DIF (r2 first, then 3 fused r16)
__device__ __forceinline__ int pos8(int f) { return ((f & 1) << 12) | rev4_12(f >> 1); }

// ---------- radix-4 butterflies ----------
__device__ __forceinline__ void dif4(float2& x0, float2& x1, float2& x2, float2& x3,
                                     float2 w1, float2 w2, float2 w3) {
  float2 a = cadd(x0, x2), b = csub(x0, x2);
  float2 c = cadd(x1, x3), d = csub(x1, x3);
  x0 = cadd(a, c);
  x1 = cmul(make_float2(b.x + d.y, b.y - d.x), w1);
  x2 = cmul(csub(a, c), w2);
  x3 = cmul(make_float2(b.x - d.y, b.y + d.x), w3);
}
__device__ __forceinline__ void dif4_nw(float2& x0, float2& x1, float2& x2, float2& x3) {
  float2 a = cadd(x0, x2), b = csub(x0, x2);
  float2 c = cadd(x1, x3), d = csub(x1, x3);
  x0 = cadd(a, c);
  x1 = make_float2(b.x + d.y, b.y - d.x);
  x2 = csub(a, c);
  x3 = make_float2(b.x - d.y, b.y + d.x);
}
// DIT: inputs 1..3 pre-multiplied by conj(w)
__device__ __forceinline__ void dit4(float2& x0, float2& x1, float2& x2, float2& x3,
                                     float2 w1, float2 w2, float2 w3) {
  float2 t0 = x0, t1 = cmulc(x1, w1), t2 = cmulc(x2, w2), t3 = cmulc(x3, w3);
  float2 a = cadd(t0, t2), b = csub(t0, t2);
  float2 c = cadd(t1, t3), d = csub(t1, t3);
  x0 = cadd(a, c);
  x1 = make_float2(b.x - d.y, b.y + d.x);
  x2 = csub(a, c);
  x3 = make_float2(b.x + d.y, b.y - d.x);
}
__device__ __forceinline__ void dit4_nw(float2& x0, float2& x1, float2& x2, float2& x3) {
  float2 a = cadd(x0, x2), b = csub(x0, x2);
  float2 c = cadd(x1, x3), d = csub(x1, x3);
  x0 = cadd(a, c);
  x1 = make_float2(b.x - d.y, b.y + d.x);
  x2 = csub(a, c);
  x3 = make_float2(b.x + d.y, b.y - d.x);
}

// triple-table read: entry = {w1, w2, w3, pad} as 2x float4
__device__ __forceinline__ void ld3(const float4* __restrict__ tab, int idx,
                                    float2& w1, float2& w2, float2& w3) {
  float4 a = tab[2 * idx];
  float4 b = tab[2 * idx + 1];
  w1 = make_float2(a.x, a.y);
  w2 = make_float2(a.z, a.w);
  w3 = make_float2(b.x, b.y);
}

// ---------- twiddle + triple tables ----------
// tw[r] = W^r = exp(-2pi i r/16384)
// T4 [t*256+u] = triples of e = 4u  + 1024t   (fwd A stageA, inv C stageB)
// T16[u]       = triples of e = 16u           (fwd A stageB, inv C stageA)
// T64[t*16+u]  = triples of e = 64u + 1024t   (fwd B stageA, inv B stageB)
// T256[u]      = triples of e = 256u          (fwd B stageB, inv B stageA)
__global__ void twiddle_kernel(float2* __restrict__ tw, float4* __restrict__ T4,
                               float4* __restrict__ T16, float4* __restrict__ T64,
                               float4* __restrict__ T256) {
  const int r = blockIdx.x * blockDim.x + threadIdx.x;
  const float C = (float)(6.283185307179586476925286766559 / 16384.0);
  if (r < NFFT) {
    float s, c;
    sincosf(C * (float)r, &s, &c);
    tw[r] = make_float2(c, -s);
  }
  const int j = r - NFFT;
  float4* tab = nullptr;
  int idx = 0, e = 0;
  if (j >= 0 && j < 1024)      { tab = T4;   idx = j;        e = 4 * (j & 255) + 1024 * (j >> 8); }
  else if (j >= 1024 && j < 1280) { tab = T16;  idx = j - 1024; e = 16 * idx; }
  else if (j >= 1280 && j < 1344) { tab = T64;  idx = j - 1280; e = 64 * (idx & 15) + 1024 * (idx >> 4); }
  else if (j >= 1344 && j < 1360) { tab = T256; idx = j - 1344; e = 256 * idx; }
  if (tab) {
    float s1, c1, s2, c2, s3, c3;
    sincosf(C * (float)e, &s1, &c1);
    sincosf(C * (float)(2 * e), &s2, &c2);
    sincosf(C * (float)(3 * e), &s3, &c3);
    tab[2 * idx]     = make_float4(c1, -s1, c2, -s2);
    tab[2 * idx + 1] = make_float4(c3, -s3, 0.f, 0.f);
  }
}

// ---------- MLP: h[o][l] (round-4 proven version) ----------
__global__ __launch_bounds__(64) void mlp_kernel(
    const float* __restrict__ z, const float* __restrict__ freq,
    const float* __restrict__ w0, const float* __restrict__ b0,
    const float* __restrict__ w1, const float* __restrict__ b1,
    const float* __restrict__ w2, const float* __restrict__ b2,
    float* __restrict__ h)            // [64][L]
{
  int l = blockIdx.x * 64 + threadIdx.x;
  float zb[EDIM];
#pragma unroll
  for (int e = 0; e < EDIM; ++e) zb[e] = z[l * EDIM + e];
  float ha[ODIM], hb[ODIM];
#pragma unroll
  for (int o = 0; o < ODIM; ++o) {
    float acc = b0[o];
#pragma unroll
    for (int e = 0; e < EDIM; ++e) acc = fmaf(zb[e], w0[e * ODIM + o], acc);
    ha[o] = sinf(freq[o] * acc);
  }
#pragma unroll
  for (int o = 0; o < ODIM; ++o) {
    float acc = b1[o];
#pragma unroll
    for (int i = 0; i < ODIM; ++i) acc = fmaf(ha[i], w1[i * ODIM + o], acc);
    hb[o] = sinf(freq[o] * acc);
  }
#pragma unroll
  for (int o = 0; o < ODIM; ++o) {
    float acc = b2[o];
#pragma unroll
    for (int i = 0; i < ODIM; ++i) acc = fmaf(hb[i], w2[i * ODIM + o], acc);
    h[o * L_SEQ + l] = sinf(freq[o] * acc);
  }
}

// ---------- k[c][l] = (h . wout[:,c]) * exp(-t[l]*|deltas[c]|) (round-4 version) ----------
#define KT_L 128
#define KT_C 64
__global__ __launch_bounds__(KT_L) void kout_kernel(
    const float* __restrict__ h, const float* __restrict__ wout,
    const float* __restrict__ t, const float* __restrict__ deltas,
    float* __restrict__ k)            // [768][L]
{
  __shared__ float hT[ODIM][KT_L];
  __shared__ float wT[ODIM][KT_C];
  const int lb = blockIdx.x % (L_SEQ / KT_L);
  const int cb = blockIdx.x / (L_SEQ / KT_L);
  const int l0 = lb * KT_L, c0 = cb * KT_C;
  const int tid = threadIdx.x;
  for (int i = tid; i < ODIM * KT_L; i += KT_L) {
    int o = i / KT_L, ll = i % KT_L;
    hT[o][ll] = h[o * L_SEQ + l0 + ll];
  }
  for (int i = tid; i < ODIM * KT_C; i += KT_L) {
    int o = i / KT_C, cc = i % KT_C;
    wT[o][cc] = wout[o * CCH + c0 + cc];
  }
  __syncthreads();
  float hv[ODIM];
#pragma unroll
  for (int o = 0; o < ODIM; ++o) hv[o] = hT[o][tid];
  const float tl = t[l0 + tid];
  for (int c = 0; c < KT_C; ++c) {
    float acc = 0.f;
#pragma unroll
    for (int o = 0; o < ODIM; ++o) acc = fmaf(hv[o], wT[o][c], acc);
    float mod = expf(-tl * fabsf(deltas[c0 + c]));
    k[(size_t)(c0 + c) * L_SEQ + l0 + tid] = acc * mod;
  }
}

// ---------- FFT rounds (8192 = r2 x 4096, two halves; 3 fused radix-16 rounds) ----------

// fwd round A fused with global load + radix-2 zero-pad twiddle (upper half)
__device__ __forceinline__ void fwd_roundA(float2* Z, const float2* __restrict__ src,
                                           const float2* __restrict__ tw,
                                           const float4* __restrict__ T4,
                                           const float4* __restrict__ T16, int tid) {
  const int h = tid >> 8, u = tid & 255;
  float2 e[4][4];
#pragma unroll
  for (int s = 0; s < 4; ++s)
#pragma unroll
    for (int t = 0; t < 4; ++t) {
      const int gi = u + s * 1024 + t * 256;
      float2 v = src[gi];
      if (h) v = cmul(v, tw[2 * gi]);
      e[s][t] = v;
    }
#pragma unroll
  for (int t = 0; t < 4; ++t) {            // stage A: span 1024, e = 4u + 1024t
    float2 w1, w2, w3;
    ld3(T4, t * 256 + u, w1, w2, w3);
    dif4(e[0][t], e[1][t], e[2][t], e[3][t], w1, w2, w3);
  }
  {                                         // stage B: span 256, e = 16u
    float2 w1, w2, w3;
    ld3(T16, u, w1, w2, w3);
#pragma unroll
    for (int s = 0; s < 4; ++s) dif4(e[s][0], e[s][1], e[s][2], e[s][3], w1, w2, w3);
  }
  const int base = (h << 12) + u;
#pragma unroll
  for (int s = 0; s < 4; ++s)
#pragma unroll
    for (int t = 0; t < 4; ++t) Z[swz(base + s * 1024 + t * 256)] = e[s][t];
}

__device__ __forceinline__ void fwd_roundB(float2* Z, const float4* __restrict__ T64,
                                           const float4* __restrict__ T256, int tid) {
  const int u = tid & 15, g = (tid >> 4) & 15, h = tid >> 8;
  const int base = (h << 12) + (g << 8) + u;
  int adr[4][4];
#pragma unroll
  for (int s = 0; s < 4; ++s)
#pragma unroll
    for (int t = 0; t < 4; ++t) adr[s][t] = swz(base + s * 64 + t * 16);
  float2 e[4][4];
#pragma unroll
  for (int s = 0; s < 4; ++s)
#pragma unroll
    for (int t = 0; t < 4; ++t) e[s][t] = Z[adr[s][t]];
#pragma unroll
  for (int t = 0; t < 4; ++t) {            // stage A: span 64, e = 64u + 1024t
    float2 w1, w2, w3;
    ld3(T64, t * 16 + u, w1, w2, w3);
    dif4(e[0][t], e[1][t], e[2][t], e[3][t], w1, w2, w3);
  }
  {                                         // stage B: span 16, e = 256u
    float2 w1, w2, w3;
    ld3(T256, u, w1, w2, w3);
#pragma unroll
    for (int s = 0; s < 4; ++s) dif4(e[s][0], e[s][1], e[s][2], e[s][3], w1, w2, w3);
  }
#pragma unroll
  for (int s = 0; s < 4; ++s)
#pragma unroll
    for (int t = 0; t < 4; ++t) Z[adr[s][t]] = e[s][t];
}

__device__ __forceinline__ void fwd_roundC(float2* Z, int tid) {
  const int h = tid >> 8, jp = tid & 255;
  const int base = (h << 12) + (jp << 4);
  int adr[4][4];
#pragma unroll
  for (int s = 0; s < 4; ++s)
#pragma unroll
    for (int t = 0; t < 4; ++t) adr[s][t] = swz(base + s * 4 + t);
  float2 e[4][4];
#pragma unroll
  for (int s = 0; s < 4; ++s)
#pragma unroll
    for (int t = 0; t < 4; ++t) e[s][t] = Z[adr[s][t]];
  // stage A: span 4, e = 1024t (constants; t=0 unit)
  dif4_nw(e[0][0], e[1][0], e[2][0], e[3][0]);
  dif4(e[0][1], e[1][1], e[2][1], e[3][1],
       make_float2(C_PI8, -S_PI8), make_float2(C_PI4, -C_PI4), make_float2(S_PI8, -C_PI8));
  dif4(e[0][2], e[1][2], e[2][2], e[3][2],
       make_float2(C_PI4, -C_PI4), make_float2(0.f, -1.f), make_float2(-C_PI4, -C_PI4));
  dif4(e[0][3], e[1][3], e[2][3], e[3][3],
       make_float2(S_PI8, -C_PI8), make_float2(-C_PI4, -C_PI4), make_float2(-C_PI8, S_PI8));
  // stage B: span 1, unit twiddles
#pragma unroll
  for (int s = 0; s < 4; ++s) dif4_nw(e[s][0], e[s][1], e[s][2], e[s][3]);
#pragma unroll
  for (int s = 0; s < 4; ++s)
#pragma unroll
    for (int t = 0; t < 4; ++t) Z[adr[s][t]] = e[s][t];
}

__device__ __forceinline__ void inv_roundA(float2* Z, int tid) {
  const int h = tid >> 8, jp = tid & 255;
  const int base = (h << 12) + (jp << 4);
  int adr[4][4];
#pragma unroll
  for (int s = 0; s < 4; ++s)
#pragma unroll
    for (int t = 0; t < 4; ++t) adr[s][t] = swz(base + s * 4 + t);
  float2 e[4][4];
#pragma unroll
  for (int s = 0; s < 4; ++s)
#pragma unroll
    for (int t = 0; t < 4; ++t) e[s][t] = Z[adr[s][t]];
  // stage A: span 1 over t, unit
#pragma unroll
  for (int s = 0; s < 4; ++s) dit4_nw(e[s][0], e[s][1], e[s][2], e[s][3]);
  // stage B: span 4 over s, e = 1024t (conj applied inside dit4)
  dit4_nw(e[0][0], e[1][0], e[2][0], e[3][0]);
  dit4(e[0][1], e[1][1], e[2][1], e[3][1],
       make_float2(C_PI8, -S_PI8), make_float2(C_PI4, -C_PI4), make_float2(S_PI8, -C_PI8));
  dit4(e[0][2], e[1][2], e[2][2], e[3][2],
       make_float2(C_PI4, -C_PI4), make_float2(0.f, -1.f), make_float2(-C_PI4, -C_PI4));
  dit4(e[0][3], e[1][3], e[2][3], e[3][3],
       make_float2(S_PI8, -C_PI8), make_float2(-C_PI4, -C_PI4), make_float2(-C_PI8, S_PI8));
#pragma unroll
  for (int s = 0; s < 4; ++s)
#pragma unroll
    for (int t = 0; t < 4; ++t) Z[adr[s][t]] = e[s][t];
}

__device__ __forceinline__ void inv_roundB(float2* Z, const float4* __restrict__ T64,
                                           const float4* __restrict__ T256, int tid) {
  const int u = tid & 15, g = (tid >> 4) & 15, h = tid >> 8;
  const int base = (h << 12) + (g << 8) + u;
  int adr[4][4];
#pragma unroll
  for (int s = 0; s < 4; ++s)
#pragma unroll
    for (int t = 0; t < 4; ++t) adr[s][t] = swz(base + s * 64 + t * 16);
  float2 e[4][4];
#pragma unroll
  for (int s = 0; s < 4; ++s)
#pragma unroll
    for (int t = 0; t < 4; ++t) e[s][t] = Z[adr[s][t]];
  {                                         // stage A: span 16 over t, e = 256u
    float2 w1, w2, w3;
    ld3(T256, u, w1, w2, w3);
#pragma unroll
    for (int s = 0; s < 4; ++s) dit4(e[s][0], e[s][1], e[s][2], e[s][3], w1, w2, w3);
  }
#pragma unroll
  for (int t = 0; t < 4; ++t) {            // stage B: span 64 over s, e = 64u + 1024t
    float2 w1, w2, w3;
    ld3(T64, t * 16 + u, w1, w2, w3);
    dit4(e[0][t], e[1][t], e[2][t], e[3][t], w1, w2, w3);
  }
#pragma unroll
  for (int s = 0; s < 4; ++s)
#pragma unroll
    for (int t = 0; t < 4; ++t) Z[adr[s][t]] = e[s][t];
}

__device__ __forceinline__ void inv_roundC(float2* Z, const float4* __restrict__ T4,
                                           const float4* __restrict__ T16, int tid) {
  const int h = tid >> 8, u = tid & 255;
  const int base = (h << 12) + u;
  int adr[4][4];
#pragma unroll
  for (int s = 0; s < 4; ++s)
#pragma unroll
    for (int t = 0; t < 4; ++t) adr[s][t] = swz(base + s * 1024 + t * 256);
  float2 e[4][4];
#pragma unroll
  for (int s = 0; s < 4; ++s)
#pragma unroll
    for (int t = 0; t < 4; ++t) e[s][t] = Z[adr[s][t]];
  {                                         // stage A: span 256 over t, e = 16u
    float2 w1, w2, w3;
    ld3(T16, u, w1, w2, w3);
#pragma unroll
    for (int s = 0; s < 4; ++s) dit4(e[s][0], e[s][1], e[s][2], e[s][3], w1, w2, w3);
  }
#pragma unroll
  for (int t = 0; t < 4; ++t) {            // stage B: span 1024 over s, e = 4u + 1024t
    float2 w1, w2, w3;
    ld3(T4, t * 256 + u, w1, w2, w3);
    dit4(e[0][t], e[1][t], e[2][t], e[3][t], w1, w2, w3);
  }
#pragma unroll
  for (int s = 0; s < 4; ++s)
#pragma unroll
    for (int t = 0; t < 4; ++t) Z[adr[s][t]] = e[s][t];
}

// ---------- kfft: one channel per WG; store K half-spectrum ----------
__global__ __launch_bounds__(BLK) void kfft_kernel(
    const float* __restrict__ kf, const float2* __restrict__ tw,
    const float4* __restrict__ T4, const float4* __restrict__ T16,
    const float4* __restrict__ T64, const float4* __restrict__ T256,
    float2* __restrict__ Kf)
{
  extern __shared__ float2 Z[];
  const int c = blockIdx.x, tid = threadIdx.x;
  const float2* k2 = (const float2*)(kf + (size_t)c * L_SEQ);
  fwd_roundA(Z, k2, tw, T4, T16, tid);
  __syncthreads();
  fwd_roundB(Z, T64, T256, tid);
  __syncthreads();
  fwd_roundC(Z, tid);
  __syncthreads();

  float2* Kc = Kf + (size_t)c * N2;
#pragma unroll
  for (int s2 = 0; s2 < 8; ++s2) {
    const int f = tid + s2 * BLK;
    if (f == 0) {
      float2 z0 = Z[swz(0)];
      Kc[0] = make_float2(z0.x + z0.y, z0.x - z0.y);   // (K[0], K[8192]) both real
      float2 z4 = Z[swz(2)];                            // pos8(4096)==2
      Kc[N4] = make_float2(z4.x, -z4.y);                // K[4096] = conj(Z[4096])
    } else {
      float2 zf = Z[swz(pos8(f))];
      float2 zg = Z[swz(pos8(N2 - f))];
      float2 E = make_float2(0.5f * (zf.x + zg.x), 0.5f * (zf.y - zg.y));
      float2 O = make_float2(0.5f * (zf.y + zg.y), -0.5f * (zf.x - zg.x));
      float2 wO = cmul(tw[f], O);
      Kc[f]      = cadd(E, wO);
      Kc[N2 - f] = cconj(csub(E, wO));
    }
  }
}

// ---------- conv: one (b,c) row per WG ----------
__global__ __launch_bounds__(BLK) void conv_kernel(
    const float* __restrict__ x, const float2* __restrict__ Kf,
    const float* __restrict__ bias, const float2* __restrict__ tw,
    const float4* __restrict__ T4, const float4* __restrict__ T16,
    const float4* __restrict__ T64, const float4* __restrict__ T256,
    float* __restrict__ out)
{
  extern __shared__ float2 Z[];
  const int tid = threadIdx.x;
  const int c = blockIdx.x % CCH;
  const int b = blockIdx.x / CCH;
  const float2* x2 = (const float2*)(x + (size_t)(b * CCH + c) * L_SEQ);

  fwd_roundA(Z, x2, tw, T4, T16, tid);
  __syncthreads();
  fwd_roundB(Z, T64, T256, tid);
  __syncthreads();
  fwd_roundC(Z, tid);
  __syncthreads();

  // unpack X, multiply by K, repack spectrum of w = y_even + i*y_odd
  const float2* Kc = Kf + (size_t)c * N2;
  const float scale = 1.0f / (float)NFFT;
#pragma unroll
  for (int s2 = 0; s2 < 8; ++s2) {
    const int f = tid + s2 * BLK;
    if (f == 0) {
      float2 z0 = Z[swz(0)];
      float2 k0 = Kc[0];
      float Y0 = (z0.x + z0.y) * k0.x * scale;
      float Y8 = (z0.x - z0.y) * k0.y * scale;
      Z[swz(0)] = make_float2(0.5f * (Y0 + Y8), 0.5f * (Y0 - Y8));
      float2 z4 = Z[swz(2)];
      float2 k4 = Kc[N4];
      float2 Y4 = cmul(make_float2(z4.x, -z4.y), k4);
      Y4.x *= scale; Y4.y *= scale;
      Z[swz(2)] = cconj(Y4);
    } else {
      const int p  = swz(pos8(f));
      const int pq = swz(pos8(N2 - f));
      float2 zf = Z[p], zg = Z[pq];
      float2 E = make_float2(0.5f * (zf.x + zg.x), 0.5f * (zf.y - zg.y));
      float2 O = make_float2(0.5f * (zf.y + zg.y), -0.5f * (zf.x - zg.x));
      float2 w = tw[f];
      float2 wO = cmul(w, O);
      float2 P = cadd(E, wO);                     // X[f]
      float2 M = csub(E, wO);                     // conj(X[8192-f])
      float2 Yf  = cmul(P, Kc[f]);
      float2 Ygc = cmul(M, cconj(Kc[N2 - f]));    // conj(Y[8192-f])
      Yf.x *= scale; Yf.y *= scale; Ygc.x *= scale; Ygc.y *= scale;
      float2 A  = make_float2(0.5f * (Yf.x + Ygc.x), 0.5f * (Yf.y + Ygc.y));
      float2 Bc = make_float2(0.5f * (Yf.x - Ygc.x), 0.5f * (Yf.y - Ygc.y));
      float2 cb  = cmul(cconj(w), Bc);
      Z[p]  = make_float2(A.x - cb.y, A.y + cb.x);
      float2 cb2 = cmul(w, cconj(Bc));
      Z[pq] = make_float2(A.x - cb2.y, -A.y + cb2.x);
    }
  }
  __syncthreads();
  inv_roundA(Z, tid);
  __syncthreads();
  inv_roundB(Z, T64, T256, tid);
  __syncthreads();
  inv_roundC(Z, T4, T16, tid);
  __syncthreads();

  // fused final radix-2 DIT (low half only) + epilogue, float2 stores
  const float bc = bias[c];
  float2* o2 = (float2*)(out + (size_t)(b * CCH + c) * L_SEQ);
#pragma unroll
  for (int i = tid; i < N4; i += BLK) {
    float2 a = Z[swz(i)];
    float2 bb = cmul(Z[swz(i + N4)], cconj(tw[2 * i]));
    float2 xv = x2[i];
    o2[i] = make_float2(a.x + bb.x + xv.x * bc, a.y + bb.y + xv.y * bc);
  }
}

extern "C" void kernel_launch(void* const* d_in, const int* in_sizes, int n_in,
                              void* d_out, int out_size, void* d_ws, size_t ws_size,
                              hipStream_t stream) {
  const float* x      = (const float*)d_in[0];
  const float* bias   = (const float*)d_in[1];
  const float* z      = (const float*)d_in[2];
  const float* t      = (const float*)d_in[3];
  const float* deltas = (const float*)d_in[4];
  const float* freq   = (const float*)d_in[5];
  const float* w0     = (const float*)d_in[6];
  const float* b0     = (const float*)d_in[7];
  const float* w1     = (const float*)d_in[8];
  const float* b1     = (const float*)d_in[9];
  const float* w2     = (const float*)d_in[10];
  const float* b2     = (const float*)d_in[11];
  const float* wout   = (const float*)d_in[12];
  float* out = (float*)d_out;

  // ws layout: [tw 128K][T4 32K][T16 8K][T64 2K][T256 .5K][h 2M][kfilt 24M][Kf 48M]
  char* p = (char*)d_ws;
  float2* tw   = (float2*)p;             p += (size_t)NFFT * sizeof(float2);
  float4* T4   = (float4*)p;             p += (size_t)1024 * 2 * sizeof(float4);
  float4* T16  = (float4*)p;             p += (size_t)256 * 2 * sizeof(float4);
  float4* T64  = (float4*)p;             p += (size_t)64 * 2 * sizeof(float4);
  float4* T256 = (float4*)p;             p += (size_t)16 * 2 * sizeof(float4);
  float*  h    = (float*)p;              p += (size_t)ODIM * L_SEQ * sizeof(float);
  float*  kfilt= (float*)p;              p += (size_t)CCH * L_SEQ * sizeof(float);
  float2* Kf   = (float2*)p;

  twiddle_kernel<<<70, 256, 0, stream>>>(tw, T4, T16, T64, T256);
  mlp_kernel<<<L_SEQ / 64, 64, 0, stream>>>(z, freq, w0, b0, w1, b1, w2, b2, h);
  kout_kernel<<<(L_SEQ / KT_L) * (CCH / KT_C), KT_L, 0, stream>>>(h, wout, t, deltas, kfilt);

  const size_t lds = (size_t)N2 * sizeof(float2);   // 64 KB
  hipFuncSetAttribute(reinterpret_cast<const void*>(kfft_kernel),
                      hipFuncAttributeMaxDynamicSharedMemorySize, lds);
  hipFuncSetAttribute(reinterpret_cast<const void*>(conv_kernel),
                      hipFuncAttributeMaxDynamicSharedMemorySize, lds);
  kfft_kernel<<<CCH, BLK, lds, stream>>>(kfilt, tw, T4, T16, T64, T256, Kf);
  conv_kernel<<<BB * CCH, BLK, lds, stream>>>(x, Kf, bias, tw, T4, T16, T64, T256, out);
}